// Round 7
// baseline (386.311 us; speedup 1.0000x reference)
//
#include <hip/hip_runtime.h>
#include <math.h>

// MeanShift R15: R14 + hand-rolled software pipeline (R14 stayed latency
// bound: VALUBusy 39%, VGPR 52 proved the compiler serialized
// ds_read->MFMA->exp->fma per tile).
//  - uP/uN MFMA double buffer: tile t+1's MFMA issues before tile t's
//    exp/PV processing (MFMAs independent: same C = ny splat).
//  - pfb0/pfb1 2-deep global prefetch of A-fragments, parity-static in a
//    2x-unrolled tile loop (no v_mov shuffle).
//  - PA/PB rolling LDS double-buffer at q-group granularity, compile-time
//    ds offsets off a per-tile pointer (ptile += 32/tile).
//  - LDS padded +8 float4: the final dead lookahead ds_read stays in-bounds.
// Structure else unchanged: QK^T on MFMA (positional packing, exact via
// bf16 hi/lo split + f32 C), PV on VALU from the HW-verified C/D layout.
//   u(n,m) = 2p'.y' - |p'|^2 - |y'|^2, w = exp2(u), num/den = w @ [p',1]

#define NPTS 9216
#define NB 2
#define TOT (NB * NPTS)
#define NTIL 288              // 32-wide n tiles per batch
#define MSPL 6                // m-chunks per batch
#define MBLK 1536             // m-points per block (= 48 tiles * 32)
#define TPW 12                // m-tiles per wave (4 waves/block)
#define LOG2E 1.44269504088896340736f

typedef float v2f __attribute__((ext_vector_type(2)));
typedef short bf16x8 __attribute__((ext_vector_type(8)));
typedef float f32x16 __attribute__((ext_vector_type(16)));

__device__ __forceinline__ unsigned short bf16r(float x) {
    unsigned u = __float_as_uint(x);
    return (unsigned short)((u + 0x7fffu + ((u >> 16) & 1u)) >> 16);
}
__device__ __forceinline__ float bf16f(unsigned short h) {
    return __uint_as_float((unsigned)h << 16);
}

__global__ __launch_bounds__(256) void ms_feat(const float* __restrict__ x,
                                               short* __restrict__ pfeat,
                                               float4* __restrict__ pts4,
                                               float s) {
    int gid = blockIdx.x * 256 + threadIdx.x;       // 0..18431
    int b = gid / NPTS, m = gid - b * NPTS;
    const float* xb = x + b * 3 * NPTS;
    float p0 = xb[m] * s, p1 = xb[NPTS + m] * s, p2 = xb[2 * NPTS + m] * s;
    float np = -fmaf(p0, p0, fmaf(p1, p1, p2 * p2));
    float a0 = 2.f * p0, a1 = 2.f * p1, a2 = 2.f * p2;
    unsigned short Ah0 = bf16r(a0), Ah1 = bf16r(a1), Ah2 = bf16r(a2);
    unsigned short Al0 = bf16r(a0 - bf16f(Ah0));
    unsigned short Al1 = bf16r(a1 - bf16f(Ah1));
    unsigned short Al2 = bf16r(a2 - bf16f(Ah2));
    unsigned short Nh = bf16r(np);
    unsigned short Nl = bf16r(np - bf16f(Nh));
    uint4* dst = (uint4*)(pfeat + (size_t)gid * 16);
    dst[0] = make_uint4((unsigned)Ah0 | ((unsigned)Ah1 << 16),
                        (unsigned)Ah2 | ((unsigned)Ah0 << 16),
                        (unsigned)Ah1 | ((unsigned)Ah2 << 16),
                        (unsigned)Al0 | ((unsigned)Al1 << 16));
    dst[1] = make_uint4((unsigned)Al2 | ((unsigned)Al0 << 16),
                        (unsigned)Al1 | ((unsigned)Al2 << 16),
                        (unsigned)Nh  | ((unsigned)Nl  << 16), 0u);
    pts4[gid] = make_float4(p0, p1, p2, 1.0f);
}

// process q-group: load next group's P into PL, exp+fma current group from PU
#define QGRP(U, q, PU0, PU1, PU2, PU3, PL0, PL1, PL2, PL3, DG, AX, AZ)      \
    {                                                                       \
        PL0 = ptile[8 * (DG) + 0];                                          \
        PL1 = ptile[8 * (DG) + 1];                                          \
        PL2 = ptile[8 * (DG) + 2];                                          \
        PL3 = ptile[8 * (DG) + 3];                                          \
        float w0 = __builtin_amdgcn_exp2f(U[4 * (q) + 0]);                  \
        float w1 = __builtin_amdgcn_exp2f(U[4 * (q) + 1]);                  \
        float w2 = __builtin_amdgcn_exp2f(U[4 * (q) + 2]);                  \
        float w3 = __builtin_amdgcn_exp2f(U[4 * (q) + 3]);                  \
        AX = __builtin_elementwise_fma((v2f){w0, w0}, (v2f){PU0.x, PU0.y}, AX); \
        AZ = __builtin_elementwise_fma((v2f){w0, w0}, (v2f){PU0.z, PU0.w}, AZ); \
        AX = __builtin_elementwise_fma((v2f){w1, w1}, (v2f){PU1.x, PU1.y}, AX); \
        AZ = __builtin_elementwise_fma((v2f){w1, w1}, (v2f){PU1.z, PU1.w}, AZ); \
        AX = __builtin_elementwise_fma((v2f){w2, w2}, (v2f){PU2.x, PU2.y}, AX); \
        AZ = __builtin_elementwise_fma((v2f){w2, w2}, (v2f){PU2.z, PU2.w}, AZ); \
        AX = __builtin_elementwise_fma((v2f){w3, w3}, (v2f){PU3.x, PU3.y}, AX); \
        AZ = __builtin_elementwise_fma((v2f){w3, w3}, (v2f){PU3.z, PU3.w}, AZ); \
    }

// full tile: issue next tile's MFMA + fragment prefetch, process current u
#define TBODY(CUR, NXT, PFB)                                                \
    {                                                                       \
        NXT = __builtin_amdgcn_mfma_f32_32x32x16_bf16(PFB, yf.v, cin, 0, 0, 0); \
        PFB = *(const bf16x8*)(pfl + 1536);                                 \
        QGRP(CUR, 0, PA0, PA1, PA2, PA3, PB0, PB1, PB2, PB3, 1, Axy0, Azw0) \
        QGRP(CUR, 1, PB0, PB1, PB2, PB3, PA0, PA1, PA2, PA3, 2, Axy1, Azw1) \
        QGRP(CUR, 2, PA0, PA1, PA2, PA3, PB0, PB1, PB2, PB3, 3, Axy0, Azw0) \
        QGRP(CUR, 3, PB0, PB1, PB2, PB3, PA0, PA1, PA2, PA3, 4, Axy1, Azw1) \
        pfl += 512;                                                         \
        ptile += 32;                                                        \
    }

#define TLAST(CUR)                                                          \
    {                                                                       \
        QGRP(CUR, 0, PA0, PA1, PA2, PA3, PB0, PB1, PB2, PB3, 1, Axy0, Azw0) \
        QGRP(CUR, 1, PB0, PB1, PB2, PB3, PA0, PA1, PA2, PA3, 2, Axy1, Azw1) \
        QGRP(CUR, 2, PA0, PA1, PA2, PA3, PB0, PB1, PB2, PB3, 3, Axy0, Azw0) \
        QGRP(CUR, 3, PB0, PB1, PB2, PB3, PA0, PA1, PA2, PA3, 4, Axy1, Azw1) \
    }

__global__ __launch_bounds__(256, 4) void ms_iter(
    const float* __restrict__ x, const float4* __restrict__ accIn,
    float4* __restrict__ accOut, const short* __restrict__ pfeat,
    const float4* __restrict__ pts4, float s, int first) {

    __shared__ float4 lds4[MBLK + 8];       // 24.1 KB (+8 lookahead pad)

    const int tid = threadIdx.x;
    const int l   = tid & 63;
    const int wv  = tid >> 6;
    const int col = l & 31;                 // n within tile
    const int hi  = l >> 5;

    int bid = blockIdx.x;
    const int b  = bid / (MSPL * NTIL);
    int r        = bid - b * (MSPL * NTIL);
    const int nt = r / MSPL;
    const int mc = r - nt * MSPL;
    const int n  = nt * 32 + col;
    const int mbase = mc * MBLK;            // block's m range start

    // ---- stage this block's 1536 P float4s into LDS (coalesced) ----
    {
        const float4* src = pts4 + (size_t)b * NPTS + mbase;
        for (int i = tid; i < MBLK; i += 256) lds4[i] = src[i];
    }

    // ---- y' for this lane's n (scaled), split to bf16 hi/lo ----
    float y0, y1, y2;
    if (first) {
        const float* xb = x + b * 3 * NPTS;
        y0 = xb[n] * s; y1 = xb[NPTS + n] * s; y2 = xb[2 * NPTS + n] * s;
    } else {
        float4 a = accIn[b * NPTS + n];
        float inv = 1.0f / a.w;
        y0 = a.x * inv; y1 = a.y * inv; y2 = a.z * inv;
    }
    float ny = -fmaf(y0, y0, fmaf(y1, y1, y2 * y2));   // exact f32, via C
    unsigned short Yh0 = bf16r(y0), Yh1 = bf16r(y1), Yh2 = bf16r(y2);
    unsigned short Yl0 = bf16r(y0 - bf16f(Yh0));
    unsigned short Yl1 = bf16r(y1 - bf16f(Yh1));
    unsigned short Yl2 = bf16r(y2 - bf16f(Yh2));
    union { unsigned w[4]; bf16x8 v; } yf;
    if (hi == 0) {
        yf.w[0] = (unsigned)Yh0 | ((unsigned)Yh1 << 16);
        yf.w[1] = (unsigned)Yh2 | ((unsigned)Yl0 << 16);
        yf.w[2] = (unsigned)Yl1 | ((unsigned)Yl2 << 16);
        yf.w[3] = (unsigned)Yh0 | ((unsigned)Yh1 << 16);
    } else {
        yf.w[0] = (unsigned)Yh2 | ((unsigned)Yl0 << 16);
        yf.w[1] = (unsigned)Yl1 | ((unsigned)Yl2 << 16);
        yf.w[2] = 0x3F803F80u;                          // (1.0, 1.0)
        yf.w[3] = 0u;
    }

    f32x16 cin;
#pragma unroll
    for (int i = 0; i < 16; ++i) cin[i] = ny;

    v2f Axy0 = (v2f){0.f, 0.f}, Azw0 = (v2f){0.f, 0.f};
    v2f Axy1 = (v2f){0.f, 0.f}, Azw1 = (v2f){0.f, 0.f};

    // per-lane pfeat pointer for current tile; advances 512 shorts/tile
    const short* pfl = pfeat + (size_t)b * NPTS * 16 +
                       (size_t)(mbase + wv * TPW * 32 + col) * 16 + 8 * hi;
    // per-wave LDS tile base (advances 32 float4/tile)
    const float4* ptile = lds4 + wv * TPW * 32 + 4 * hi;

    f32x16 uP, uN;
    float4 PA0, PA1, PA2, PA3, PB0, PB1, PB2, PB3;

    // ---- pipeline prologue ----
    bf16x8 f0   = *(const bf16x8*)(pfl);            // tile 0 fragment
    bf16x8 pfb1 = *(const bf16x8*)(pfl + 512);      // tile 1
    bf16x8 pfb0 = *(const bf16x8*)(pfl + 1024);     // tile 2

    __syncthreads();

    uP = __builtin_amdgcn_mfma_f32_32x32x16_bf16(f0, yf.v, cin, 0, 0, 0);
    PA0 = ptile[0]; PA1 = ptile[1]; PA2 = ptile[2]; PA3 = ptile[3];

    // ---- steady state: tiles 0..9 (phases use static pfb parity) ----
    for (int t2 = 0; t2 < TPW - 2; t2 += 2) {
        TBODY(uP, uN, pfb1)     // process tile t2,   issue MFMA tile t2+1
        TBODY(uN, uP, pfb0)     // process tile t2+1, issue MFMA tile t2+2
    }
    TBODY(uP, uN, pfb1)         // tile 10, issue MFMA tile 11
    TLAST(uN)                   // tile 11

    v2f Axy = Axy0 + Axy1;
    v2f Azw = Azw0 + Azw1;

    // halves hold disjoint m-sets for the same n: combine h1 into h0.
    float hx = __shfl(Axy[0], col + 32);
    float hy = __shfl(Axy[1], col + 32);
    float hz = __shfl(Azw[0], col + 32);
    float hd = __shfl(Azw[1], col + 32);
    if (l < 32) {
        float* dst = (float*)&accOut[b * NPTS + n];
        atomicAdd(dst + 0, Axy[0] + hx);
        atomicAdd(dst + 1, Axy[1] + hy);
        atomicAdd(dst + 2, Azw[0] + hz);
        atomicAdd(dst + 3, Azw[1] + hd);
    }
}

__global__ __launch_bounds__(256) void ms_pack(const float4* __restrict__ acc4,
                                               float* __restrict__ out,
                                               float invs) {
    int gid = blockIdx.x * 256 + threadIdx.x;
    int b = gid / NPTS;
    int n = gid - b * NPTS;
    float4 a = acc4[gid];
    float f = invs / a.w;                   // unscale + normalize
    float* ob = out + b * 3 * NPTS;
    ob[n]            = a.x * f;
    ob[NPTS + n]     = a.y * f;
    ob[2 * NPTS + n] = a.z * f;
}

extern "C" void kernel_launch(void* const* d_in, const int* in_sizes, int n_in,
                              void* d_out, int out_size, void* d_ws, size_t ws_size,
                              hipStream_t stream) {
    const float* x = (const float*)d_in[0];
    float* out = (float*)d_out;
    float s = sqrtf(50.0f * LOG2E);

    float4* acc   = (float4*)d_ws;                      // 5*TOT*16B = 1.47MB
    short*  pfeat = (short*)(acc + (size_t)5 * TOT);    // TOT*16*2B = 590KB
    float4* pts4  = (float4*)(pfeat + (size_t)TOT * 16);// TOT*16B = 295KB

    hipMemsetAsync(acc, 0, (size_t)5 * TOT * sizeof(float4), stream);
    ms_feat<<<TOT / 256, 256, 0, stream>>>(x, pfeat, pts4, s);

    for (int it = 0; it < 5; ++it) {
        const float4* accIn = (it == 0) ? nullptr : acc + (size_t)(it - 1) * TOT;
        ms_iter<<<NB * NTIL * MSPL, 256, 0, stream>>>(
            x, accIn, acc + (size_t)it * TOT, pfeat, pts4, s, it == 0 ? 1 : 0);
    }
    ms_pack<<<TOT / 256, 256, 0, stream>>>(acc + (size_t)4 * TOT, out, 1.0f / s);
}

// Round 8
// 282.219 us; speedup vs baseline: 1.3688x; 1.3688x over previous
//
#include <hip/hip_runtime.h>
#include <math.h>

// MeanShift R16: full MFMA attention. QK^T on MFMA (unchanged, verified
// R12-R15). PV now ALSO on MFMA, with the P->bf16 B-fragment pack done via
// bit-exact primitives (bits+0x8000 round, v_perm_b32 byte select) instead
// of v_cvt_pk_bf16_f32 -- the ONLY unverified link in the failing R9/R10/R11
// chain (every other layout fact is proven by a passing kernel: C/D map by
// R12+, A-row/B-col = l&31 and kA=kB by QK^T; k-map and element-order cancel
// positionally between PV's A and B operands).
//   u(n,m) = 2p'.y' - |p'|^2 - |y'|^2 (scaled, s^2 = 50*log2e)
//   w = exp2(u); num/den = w @ [p',1]
// B content: pos(2i)=w(u[2i]) low half, pos(2i+1)=w(u[2i+1]) high half;
// m-rows crow(r,hi)=(r&3)+8(r>>2)+4hi are consecutive within each pair.
// A content (V rows [phx,phy,phz,1,plx,ply,plz,0]): pos j -> V[c][m0+MA],
// MA = 4hi+j (j<4), 8+4hi+(j-4) (j>=4) -- consecutive within pairs too.
// No LDS. u double-buffer + pf/V prefetch; last double-iter peeled (no OOB).

#define NPTS 9216
#define NB 2
#define TOT (NB * NPTS)
#define NTIL 288              // 32-wide n tiles per batch
#define MSPL 6                // m-chunks per batch
#define MBLK 1536             // m-points per chunk (= 48 tiles * 32)
#define TPW 12                // m-tiles per wave (4 waves/block)
#define LOG2E 1.44269504088896340736f

typedef short bf16x4 __attribute__((ext_vector_type(4)));
typedef short bf16x8 __attribute__((ext_vector_type(8)));
typedef float f32x16 __attribute__((ext_vector_type(16)));
typedef union { bf16x4 q[4]; bf16x8 h[2]; } vfrag;

__device__ __forceinline__ unsigned short bf16r(float x) {
    unsigned u = __float_as_uint(x);
    return (unsigned short)((u + 0x7fffu + ((u >> 16) & 1u)) >> 16);
}
__device__ __forceinline__ float bf16f(unsigned short h) {
    return __uint_as_float((unsigned)h << 16);
}

// Pfeat[b][m][16] bf16 slots (positional, = R14): [Ahx,Ahy,Ahz,Ahx,Ahy,Ahz,
//   Alx,Aly | Alz,Alx,Aly,Alz,Nh,Nl,0,0],  A=2p', N=-|p'|^2
// Vfeat[b][8][m] bf16 rows: [phx,phy,phz, 1, plx,ply,plz, 0]
__global__ __launch_bounds__(256) void ms_feat(const float* __restrict__ x,
                                               short* __restrict__ pfeat,
                                               short* __restrict__ vfeat,
                                               float s) {
    int gid = blockIdx.x * 256 + threadIdx.x;       // 0..18431
    int b = gid / NPTS, m = gid - b * NPTS;
    const float* xb = x + b * 3 * NPTS;
    float p0 = xb[m] * s, p1 = xb[NPTS + m] * s, p2 = xb[2 * NPTS + m] * s;
    float np = -fmaf(p0, p0, fmaf(p1, p1, p2 * p2));
    float a0 = 2.f * p0, a1 = 2.f * p1, a2 = 2.f * p2;
    unsigned short Ah0 = bf16r(a0), Ah1 = bf16r(a1), Ah2 = bf16r(a2);
    unsigned short Al0 = bf16r(a0 - bf16f(Ah0));
    unsigned short Al1 = bf16r(a1 - bf16f(Ah1));
    unsigned short Al2 = bf16r(a2 - bf16f(Ah2));
    unsigned short Nh = bf16r(np);
    unsigned short Nl = bf16r(np - bf16f(Nh));
    uint4* dst = (uint4*)(pfeat + (size_t)gid * 16);
    dst[0] = make_uint4((unsigned)Ah0 | ((unsigned)Ah1 << 16),
                        (unsigned)Ah2 | ((unsigned)Ah0 << 16),
                        (unsigned)Ah1 | ((unsigned)Ah2 << 16),
                        (unsigned)Al0 | ((unsigned)Al1 << 16));
    dst[1] = make_uint4((unsigned)Al2 | ((unsigned)Al0 << 16),
                        (unsigned)Al1 | ((unsigned)Al2 << 16),
                        (unsigned)Nh  | ((unsigned)Nl  << 16), 0u);
    unsigned short Vh0 = bf16r(p0), Vh1 = bf16r(p1), Vh2 = bf16r(p2);
    unsigned short Vl0 = bf16r(p0 - bf16f(Vh0));
    unsigned short Vl1 = bf16r(p1 - bf16f(Vh1));
    unsigned short Vl2 = bf16r(p2 - bf16f(Vh2));
    short* vb = vfeat + (size_t)b * 8 * NPTS + m;
    vb[0]        = (short)Vh0;
    vb[NPTS]     = (short)Vh1;
    vb[2 * NPTS] = (short)Vh2;
    vb[3 * NPTS] = (short)0x3F80;   // 1.0 bf16 (den row)
    vb[4 * NPTS] = (short)Vl0;
    vb[5 * NPTS] = (short)Vl1;
    vb[6 * NPTS] = (short)Vl2;
    vb[7 * NPTS] = 0;
}

// V fragment for one tile (4x 8B loads at P, P+8, P+16, P+24 shorts)
#define VLOAD(VD, P)                                                        \
    {                                                                       \
        VD.q[0] = *(const bf16x4*)(P);                                      \
        VD.q[1] = *(const bf16x4*)((P) + 8);                                \
        VD.q[2] = *(const bf16x4*)((P) + 16);                               \
        VD.q[3] = *(const bf16x4*)((P) + 24);                               \
    }

// exp2 + round-to-bf16 pack (bit-exact: +0x8000 then byte-perm) + 2 PV MFMA
#define PROC(U, VD)                                                         \
    {                                                                       \
        unsigned t0  = __float_as_uint(__builtin_amdgcn_exp2f(U[0]))  + 0x8000u; \
        unsigned t1  = __float_as_uint(__builtin_amdgcn_exp2f(U[1]))  + 0x8000u; \
        unsigned t2  = __float_as_uint(__builtin_amdgcn_exp2f(U[2]))  + 0x8000u; \
        unsigned t3  = __float_as_uint(__builtin_amdgcn_exp2f(U[3]))  + 0x8000u; \
        unsigned t4  = __float_as_uint(__builtin_amdgcn_exp2f(U[4]))  + 0x8000u; \
        unsigned t5  = __float_as_uint(__builtin_amdgcn_exp2f(U[5]))  + 0x8000u; \
        unsigned t6  = __float_as_uint(__builtin_amdgcn_exp2f(U[6]))  + 0x8000u; \
        unsigned t7  = __float_as_uint(__builtin_amdgcn_exp2f(U[7]))  + 0x8000u; \
        unsigned t8  = __float_as_uint(__builtin_amdgcn_exp2f(U[8]))  + 0x8000u; \
        unsigned t9  = __float_as_uint(__builtin_amdgcn_exp2f(U[9]))  + 0x8000u; \
        unsigned t10 = __float_as_uint(__builtin_amdgcn_exp2f(U[10])) + 0x8000u; \
        unsigned t11 = __float_as_uint(__builtin_amdgcn_exp2f(U[11])) + 0x8000u; \
        unsigned t12 = __float_as_uint(__builtin_amdgcn_exp2f(U[12])) + 0x8000u; \
        unsigned t13 = __float_as_uint(__builtin_amdgcn_exp2f(U[13])) + 0x8000u; \
        unsigned t14 = __float_as_uint(__builtin_amdgcn_exp2f(U[14])) + 0x8000u; \
        unsigned t15 = __float_as_uint(__builtin_amdgcn_exp2f(U[15])) + 0x8000u; \
        union { unsigned w[4]; bf16x8 v; } F0, F1;                          \
        F0.w[0] = __builtin_amdgcn_perm(t1,  t0,  0x07060302u);             \
        F0.w[1] = __builtin_amdgcn_perm(t3,  t2,  0x07060302u);             \
        F0.w[2] = __builtin_amdgcn_perm(t5,  t4,  0x07060302u);             \
        F0.w[3] = __builtin_amdgcn_perm(t7,  t6,  0x07060302u);             \
        F1.w[0] = __builtin_amdgcn_perm(t9,  t8,  0x07060302u);             \
        F1.w[1] = __builtin_amdgcn_perm(t11, t10, 0x07060302u);             \
        F1.w[2] = __builtin_amdgcn_perm(t13, t12, 0x07060302u);             \
        F1.w[3] = __builtin_amdgcn_perm(t15, t14, 0x07060302u);             \
        po = __builtin_amdgcn_mfma_f32_32x32x16_bf16(VD.h[0], F0.v, po, 0, 0, 0); \
        po = __builtin_amdgcn_mfma_f32_32x32x16_bf16(VD.h[1], F1.v, po, 0, 0, 0); \
    }

__global__ __launch_bounds__(256, 3) void ms_iter(
    const float* __restrict__ x, const float4* __restrict__ accIn,
    float4* __restrict__ accOut, const short* __restrict__ pfeat,
    const short* __restrict__ vfeat, float s, int first) {

    const int tid = threadIdx.x;
    const int l   = tid & 63;
    const int wv  = tid >> 6;
    const int col = l & 31;                 // n within tile; V row (clamped)
    const int hi  = l >> 5;

    int bid = blockIdx.x;
    const int b  = bid / (MSPL * NTIL);
    int r        = bid - b * (MSPL * NTIL);
    const int nt = r / MSPL;
    const int mc = r - nt * MSPL;
    const int n  = nt * 32 + col;
    const int mbase = mc * MBLK;

    // ---- y' for this lane's n (scaled), split to bf16 hi/lo ----
    float y0, y1, y2;
    if (first) {
        const float* xb = x + b * 3 * NPTS;
        y0 = xb[n] * s; y1 = xb[NPTS + n] * s; y2 = xb[2 * NPTS + n] * s;
    } else {
        float4 a = accIn[b * NPTS + n];
        float inv = 1.0f / a.w;
        y0 = a.x * inv; y1 = a.y * inv; y2 = a.z * inv;
    }
    float ny = -fmaf(y0, y0, fmaf(y1, y1, y2 * y2));   // exact f32, via C
    unsigned short Yh0 = bf16r(y0), Yh1 = bf16r(y1), Yh2 = bf16r(y2);
    unsigned short Yl0 = bf16r(y0 - bf16f(Yh0));
    unsigned short Yl1 = bf16r(y1 - bf16f(Yh1));
    unsigned short Yl2 = bf16r(y2 - bf16f(Yh2));
    union { unsigned w[4]; bf16x8 v; } yf;
    if (hi == 0) {
        yf.w[0] = (unsigned)Yh0 | ((unsigned)Yh1 << 16);
        yf.w[1] = (unsigned)Yh2 | ((unsigned)Yl0 << 16);
        yf.w[2] = (unsigned)Yl1 | ((unsigned)Yl2 << 16);
        yf.w[3] = (unsigned)Yh0 | ((unsigned)Yh1 << 16);
    } else {
        yf.w[0] = (unsigned)Yh2 | ((unsigned)Yl0 << 16);
        yf.w[1] = (unsigned)Yl1 | ((unsigned)Yl2 << 16);
        yf.w[2] = 0x3F803F80u;                          // (1.0, 1.0)
        yf.w[3] = 0u;
    }

    f32x16 cin, po;
#pragma unroll
    for (int i = 0; i < 16; ++i) cin[i] = ny;
#pragma unroll
    for (int i = 0; i < 16; ++i) po[i] = 0.f;

    // per-lane A-fragment pointer (advances 512 shorts/tile)
    const short* pfl = pfeat + (size_t)b * NPTS * 16 +
                       (size_t)(mbase + wv * TPW * 32 + col) * 16 + 8 * hi;
    // per-lane V pointer: row = min(col,7) (row 7 is all-zero), + 4*hi
    const int cmin = col < 8 ? col : 7;
    const short* vp = vfeat + (size_t)b * 8 * NPTS + (size_t)cmin * NPTS +
                      (mbase + wv * TPW * 32) + 4 * hi;

    // ---- prologue: tiles 0,1 staged ----
    bf16x8 pfA = *(const bf16x8*)(pfl);           // frag t0
    bf16x8 pfB = *(const bf16x8*)(pfl + 512);     // frag t1
    vfrag VA, VB;
    VLOAD(VA, vp)                                  // V t0
    VLOAD(VB, vp + 32)                             // V t1
    f32x16 uA = __builtin_amdgcn_mfma_f32_32x32x16_bf16(pfA, yf.v, cin, 0, 0, 0);
    f32x16 uB;

    // ---- steady state: 5 double-iterations process tiles 0..9 ----
    for (int i = 0; i < (TPW - 2) / 2; ++i) {
        // phase A: process tile 2i, issue QK^T 2i+1, prefetch frag/V 2i+2
        uB = __builtin_amdgcn_mfma_f32_32x32x16_bf16(pfB, yf.v, cin, 0, 0, 0);
        pfA = *(const bf16x8*)(pfl + 1024);
        PROC(uA, VA)
        VLOAD(VA, vp + 64)
        pfl += 512; vp += 32;
        // phase B: process tile 2i+1, issue QK^T 2i+2, prefetch 2i+3
        uA = __builtin_amdgcn_mfma_f32_32x32x16_bf16(pfA, yf.v, cin, 0, 0, 0);
        pfB = *(const bf16x8*)(pfl + 1024);
        PROC(uB, VB)
        VLOAD(VB, vp + 64)
        pfl += 512; vp += 32;
    }
    // ---- peeled tail: tiles 10, 11 (no further loads -> no overread) ----
    uB = __builtin_amdgcn_mfma_f32_32x32x16_bf16(pfB, yf.v, cin, 0, 0, 0);
    PROC(uA, VA)
    PROC(uB, VB)

    // po rows (C/D map): hi=0 regs 0-3 = [num_hi_x, num_hi_y, num_hi_z, den];
    // hi=1 regs 0-2 = rows 4-6 = [num_lo_x, num_lo_y, num_lo_z]
    float lx = __shfl(po[0], col + 32);
    float ly = __shfl(po[1], col + 32);
    float lz = __shfl(po[2], col + 32);
    if (l < 32) {
        float* dst = (float*)&accOut[b * NPTS + n];
        atomicAdd(dst + 0, po[0] + lx);
        atomicAdd(dst + 1, po[1] + ly);
        atomicAdd(dst + 2, po[2] + lz);
        atomicAdd(dst + 3, po[3]);
    }
}

__global__ __launch_bounds__(256) void ms_pack(const float4* __restrict__ acc4,
                                               float* __restrict__ out,
                                               float invs) {
    int gid = blockIdx.x * 256 + threadIdx.x;
    int b = gid / NPTS;
    int n = gid - b * NPTS;
    float4 a = acc4[gid];
    float f = invs / a.w;                   // unscale + normalize
    float* ob = out + b * 3 * NPTS;
    ob[n]            = a.x * f;
    ob[NPTS + n]     = a.y * f;
    ob[2 * NPTS + n] = a.z * f;
}

extern "C" void kernel_launch(void* const* d_in, const int* in_sizes, int n_in,
                              void* d_out, int out_size, void* d_ws, size_t ws_size,
                              hipStream_t stream) {
    const float* x = (const float*)d_in[0];
    float* out = (float*)d_out;
    float s = sqrtf(50.0f * LOG2E);

    float4* acc   = (float4*)d_ws;                      // 5*TOT*16B = 1.47MB
    short*  pfeat = (short*)(acc + (size_t)5 * TOT);    // TOT*16*2B = 590KB
    short*  vfeat = pfeat + (size_t)TOT * 16;           // NB*8*NPTS*2B = 295KB

    hipMemsetAsync(acc, 0, (size_t)5 * TOT * sizeof(float4), stream);
    ms_feat<<<TOT / 256, 256, 0, stream>>>(x, pfeat, vfeat, s);

    for (int it = 0; it < 5; ++it) {
        const float4* accIn = (it == 0) ? nullptr : acc + (size_t)(it - 1) * TOT;
        ms_iter<<<NB * NTIL * MSPL, 256, 0, stream>>>(
            x, accIn, acc + (size_t)it * TOT, pfeat, vfeat, s, it == 0 ? 1 : 0);
    }
    ms_pack<<<TOT / 256, 256, 0, stream>>>(acc + (size_t)4 * TOT, out, 1.0f / s);
}